// Round 12
// baseline (1072.494 us; speedup 1.0000x reference)
//
#include <hip/hip_runtime.h>
#include <hip/hip_bf16.h>

#define TOK   8192      // B*S
#define HD    1024      // H
#define FD    4096      // F
#define NE    8         // E
#define TOPK  2
#define NPAIR (TOK*TOPK)   // 16384, fixed
#define PADR  256          // row padding for tile overrun
#define BM    128
#define BN    256
#define BK    64
#define MAXT  (NPAIR/BM + NE)   // 136: upper bound on total row tiles

typedef short bf16x8 __attribute__((ext_vector_type(8)));
typedef float f32x4  __attribute__((ext_vector_type(4)));

__device__ inline unsigned short f2bf(float f) {
    unsigned u = __float_as_uint(f);
    unsigned r = (u + 0x7fffu + ((u >> 16) & 1u)) >> 16;
    return (unsigned short)r;
}

// ---------------- transpose + fp32->bf16 convert: in [E][R][C] -> out [E][C][R]
template<int R, int C>
__global__ __launch_bounds__(256) void transpose_cvt_kernel(
    const float* __restrict__ in, short* __restrict__ out)
{
    __shared__ float tile[64][65];
    const int tid = threadIdx.x;
    const int c0 = blockIdx.x * 64, r0 = blockIdx.y * 64, e = blockIdx.z;
    #pragma unroll
    for (int i = 0; i < 4; ++i) {
        int idx = i * 1024 + tid * 4;
        int rr = idx >> 6, cc = idx & 63;
        float4 v = *(const float4*)&in[((size_t)e * R + r0 + rr) * C + c0 + cc];
        tile[rr][cc] = v.x; tile[rr][cc + 1] = v.y;
        tile[rr][cc + 2] = v.z; tile[rr][cc + 3] = v.w;
    }
    __syncthreads();
    #pragma unroll
    for (int i = 0; i < 8; ++i) {
        int idx = i * 256 + tid;
        int cc = idx >> 5, rp = idx & 31;
        unsigned lo = f2bf(tile[rp * 2][cc]);
        unsigned hi = f2bf(tile[rp * 2 + 1][cc]);
        unsigned w = lo | (hi << 16);
        *(unsigned*)&out[((size_t)e * C + c0 + cc) * R + r0 + rp * 2] = w;
    }
}

// ---------------- gating: fp64 LN + logits + softmax + top-2 (one wave per token)
__global__ __launch_bounds__(256) void gating_kernel(
    const float* __restrict__ x, const float* __restrict__ gn_g, const float* __restrict__ gn_b,
    const float* __restrict__ gate_w, const float* __restrict__ gate_b,
    int* __restrict__ topk_i, float* __restrict__ topk_w, int* __restrict__ counts)
{
    const int wv = threadIdx.x >> 6, lane = threadIdx.x & 63;
    const int t = blockIdx.x * 4 + wv;
    const float* xr = x + (size_t)t * HD;

    double xs[16];
    #pragma unroll
    for (int i = 0; i < 16; ++i) xs[i] = (double)xr[i * 64 + lane];
    double s = 0.0;
    #pragma unroll
    for (int i = 0; i < 16; ++i) s += xs[i];
    #pragma unroll
    for (int o = 32; o > 0; o >>= 1) s += __shfl_xor(s, o, 64);
    double mean = s * (1.0 / HD);
    double ss = 0.0;
    #pragma unroll
    for (int i = 0; i < 16; ++i) { double d = xs[i] - mean; ss += d * d; }
    #pragma unroll
    for (int o = 32; o > 0; o >>= 1) ss += __shfl_xor(ss, o, 64);
    double inv = 1.0 / sqrt(ss * (1.0 / HD) + 1e-5);

    double ac[NE];
    #pragma unroll
    for (int e = 0; e < NE; ++e) ac[e] = 0.0;
    #pragma unroll
    for (int i = 0; i < 16; ++i) {
        int h = i * 64 + lane;
        double ln = (xs[i] - mean) * inv * (double)gn_g[h] + (double)gn_b[h];
        #pragma unroll
        for (int e = 0; e < NE; ++e) ac[e] += ln * (double)gate_w[h * NE + e];
    }
    #pragma unroll
    for (int e = 0; e < NE; ++e) {
        #pragma unroll
        for (int o = 32; o > 0; o >>= 1) ac[e] += __shfl_xor(ac[e], o, 64);
    }
    if (lane == 0) {
        double lg[NE], p[NE];
        double mx = -1e300;
        #pragma unroll
        for (int e = 0; e < NE; ++e) { lg[e] = ac[e] + (double)gate_b[e]; mx = lg[e] > mx ? lg[e] : mx; }
        double ps = 0.0;
        #pragma unroll
        for (int e = 0; e < NE; ++e) { p[e] = exp(lg[e] - mx); ps += p[e]; }
        #pragma unroll
        for (int e = 0; e < NE; ++e) p[e] /= ps;
        int i0 = 0;
        for (int e = 1; e < NE; ++e) if (p[e] > p[i0]) i0 = e;   // strict > keeps first (jax tie rule)
        int i1 = (i0 == 0) ? 1 : 0;
        for (int e = 0; e < NE; ++e) if (e != i0 && p[e] > p[i1]) i1 = e;
        double den = p[i0] + p[i1] + 1e-9;
        topk_i[t * 2] = i0; topk_i[t * 2 + 1] = i1;
        topk_w[t * 2] = (float)(p[i0] / den);
        topk_w[t * 2 + 1] = (float)(p[i1] / den);
        atomicAdd(&counts[i0], 1);
        atomicAdd(&counts[i1], 1);
    }
}

// ---------------- tiny prefix sums: row offsets + 128-row tile prefix
__global__ void offsets_kernel(const int* __restrict__ counts,
                               int* __restrict__ offs, int* __restrict__ ts)
{
    if (threadIdx.x == 0) {
        int s = 0, t = 0;
        for (int e = 0; e < NE; ++e) {
            offs[e] = s; ts[e] = t;
            s += counts[e];
            t += (counts[e] + BM - 1) / BM;
        }
        offs[NE] = s; ts[NE] = t;
    }
}

// ---------------- scatter pair ids into expert-grouped list (+ inverse map)
__global__ __launch_bounds__(256) void scatter_kernel(
    const int* __restrict__ topk_i, const int* __restrict__ offs,
    int* __restrict__ cursor, int* __restrict__ pair_tok, int* __restrict__ inv_row)
{
    int idx = blockIdx.x * 256 + threadIdx.x;   // pair id = t*2+k
    if (idx < NPAIR) {
        int e = topk_i[idx];
        int pos = atomicAdd(&cursor[e], 1);
        int dst = offs[e] + pos;
        pair_tok[dst] = idx;
        inv_row[idx] = dst;
    }
}

// ---------------- gather x rows (fp32) -> Xg (bf16, grouped order)
__global__ __launch_bounds__(256) void gather_kernel(
    const float* __restrict__ x, const int* __restrict__ pair_tok, short* __restrict__ Xg)
{
    const int r = blockIdx.x;
    const int t = pair_tok[r] >> 1;
    const int tid = threadIdx.x;
    float4 v = *(const float4*)&x[(size_t)t * HD + tid * 4];
    unsigned w0 = (unsigned)f2bf(v.x) | ((unsigned)f2bf(v.y) << 16);
    unsigned w1 = (unsigned)f2bf(v.z) | ((unsigned)f2bf(v.w) << 16);
    *(uint2*)&Xg[(size_t)r * HD + tid * 4] = make_uint2(w0, w1);
}

#define GLOAD(srcp, dstp) __builtin_amdgcn_global_load_lds(                         \
        (const __attribute__((address_space(1))) unsigned*)(srcp),                  \
        (__attribute__((address_space(3))) unsigned*)(dstp), 16, 0, 0)

// ---------------- grouped GEMM, 128x256 work items, BK=64, 2 LDS dbufs (96 KB),
// PERSISTENT blocks (grid=256, 1 blk/CU) + atomic work counter: each block grabs
// flat items w=(tile j, col c) until drained -> near-perfect load balance (the
// r5-r11 plateau was tail idling from block-to-(expert,slot) quantization, not
// schedule quality). Item order: cols of one tile adjacent -> A-panel L2 reuse.
// K-loop = r11's m230-style 2-phase: STAGE next (6 gloads); ks0 frags; 16 MFMA;
// ks1 frags; 16 MFMA; __syncthreads() (implicit vmcnt(0) drains loads issued a
// full K-tile earlier -> hidden). Granule swizzle (verified conflict-free r6/r7):
// phys 16B-granule g of row r holds global granule g^(r&7), pre-swizzled global
// source + swizzled ds_read addr (rule #21).
// EPI==1: gelu -> bf16 Hbuf ; EPI==2: +bias -> fp32 Op (both grouped rows)
template<int KDIM, int NDIM, int EPI, int NCOL>
__global__ __launch_bounds__(512, 2) void gemm_kernel(
    const short* __restrict__ A, const short* __restrict__ BT,
    const float* __restrict__ bias, void* __restrict__ outp,
    const int* __restrict__ counts, const int* __restrict__ offs,
    const int* __restrict__ ts, int* __restrict__ wctr)
{
    __shared__ __align__(16) short As[2 * BM * BK];   // 2 x 16 KB
    __shared__ __align__(16) short Bs[2 * BN * BK];   // 2 x 32 KB
    __shared__ int witem;

    const int tid = threadIdx.x;
    const int lane = tid & 63;
    const int wv = tid >> 6;                  // 8 waves: 2 M-groups x 4 N-groups
    const int wr = (wv >> 2) * 64, wc = (wv & 3) * 64;
    const int l15 = lane & 15, l4 = lane >> 4;

    // ds_read offsets (shorts): row r, ks0 granule l4; ks1 = off ^ 32
    int aoff[4], boff[4];
    #pragma unroll
    for (int m = 0; m < 4; ++m) {
        int r = wr + m * 16 + l15;
        aoff[m] = r * BK + ((l4 ^ (r & 7)) << 3);
    }
    #pragma unroll
    for (int n = 0; n < 4; ++n) {
        int r = wc + n * 16 + l15;
        boff[n] = r * BK + ((l4 ^ (r & 7)) << 3);
    }

    // staging: (row = tid>>3 within 64-row chunk, granule = tid&7)
    const int srow = tid >> 3;                // 0..63
    const int skoff = ((tid & 7) ^ (srow & 7)) << 3;   // pre-swizzled k (shorts)
    const int dlds = tid * 8;

    const int total = ts[NE] * NCOL;

    for (;;) {
        __syncthreads();   // prior item's LDS readers done; also pairs with witem write
        if (tid == 0) witem = atomicAdd(wctr, 1);
        __syncthreads();
        const int w = witem;
        if (w >= total) break;                // block-uniform

        const int j = w / NCOL, cix = w % NCOL;   // NCOL = 16 or 4 -> shifts
        int e = 0;
        #pragma unroll
        for (int k = 1; k < NE; ++k) if (j >= ts[k]) e = k;
        const int cnt = counts[e];
        const int rt = j - ts[e];
        const int rowbase = offs[e] + rt * BM;
        const int colbase = cix * BN;
        const size_t bbase = (size_t)e * NDIM + colbase;

#define STAGE(db, kb) do {                                                           \
        _Pragma("unroll")                                                            \
        for (int s = 0; s < 2; ++s)                                                  \
            GLOAD(A + (size_t)(rowbase + s * 64 + srow) * KDIM + (kb) + skoff,       \
                  &As[(db) * (BM * BK) + s * 4096 + dlds]);                          \
        _Pragma("unroll")                                                            \
        for (int q = 0; q < 4; ++q)                                                  \
            GLOAD(BT + (bbase + q * 64 + srow) * KDIM + (kb) + skoff,                \
                  &Bs[(db) * (BN * BK) + q * 4096 + dlds]);                          \
    } while (0)

        STAGE(0, 0);
        __syncthreads();   // drains vmcnt(0): tile 0 resident

        f32x4 acc[4][4];
        #pragma unroll
        for (int m = 0; m < 4; ++m)
            #pragma unroll
            for (int n = 0; n < 4; ++n)
                acc[m][n] = (f32x4){0.f, 0.f, 0.f, 0.f};

        constexpr int NKT = KDIM / BK;
        for (int kt = 0; kt < NKT; ++kt) {
            if (kt + 1 < NKT) STAGE((kt + 1) & 1, (kt + 1) * BK);

            const short* asl = &As[(kt & 1) * (BM * BK)];
            const short* bsl = &Bs[(kt & 1) * (BN * BK)];

            {   // half 1: ks0
                bf16x8 a[4], b[4];
                #pragma unroll
                for (int m = 0; m < 4; ++m) a[m] = *(const bf16x8*)&asl[aoff[m]];
                #pragma unroll
                for (int n = 0; n < 4; ++n) b[n] = *(const bf16x8*)&bsl[boff[n]];
                __builtin_amdgcn_s_setprio(1);
                #pragma unroll
                for (int m = 0; m < 4; ++m)
                    #pragma unroll
                    for (int n = 0; n < 4; ++n)
                        acc[m][n] = __builtin_amdgcn_mfma_f32_16x16x32_bf16(a[m], b[n], acc[m][n], 0, 0, 0);
                __builtin_amdgcn_s_setprio(0);
            }
            {   // half 2: ks1
                bf16x8 a[4], b[4];
                #pragma unroll
                for (int m = 0; m < 4; ++m) a[m] = *(const bf16x8*)&asl[aoff[m] ^ 32];
                #pragma unroll
                for (int n = 0; n < 4; ++n) b[n] = *(const bf16x8*)&bsl[boff[n] ^ 32];
                __builtin_amdgcn_s_setprio(1);
                #pragma unroll
                for (int m = 0; m < 4; ++m)
                    #pragma unroll
                    for (int n = 0; n < 4; ++n)
                        acc[m][n] = __builtin_amdgcn_mfma_f32_16x16x32_bf16(a[m], b[n], acc[m][n], 0, 0, 0);
                __builtin_amdgcn_s_setprio(0);
            }

            __syncthreads();   // single drain per K-tile; next tile's loads were
                               // issued ~32 MFMAs ago
        }
#undef STAGE

        const int rmax = cnt - rt * BM;   // valid rows (tail tiles < BM)

        if (EPI == 1) {
            short* Hb = (short*)outp;
            #pragma unroll
            for (int n = 0; n < 4; ++n) {
                int col = colbase + wc + n * 16 + l15;
                float bv = bias[e * NDIM + col];
                #pragma unroll
                for (int m = 0; m < 4; ++m) {
                    int r0l = wr + m * 16 + l4 * 4;
                    #pragma unroll
                    for (int r = 0; r < 4; ++r) {
                        int rl = r0l + r;
                        if (rl < rmax) {   // guard: do NOT clobber next expert's rows
                            float vv = acc[m][n][r] + bv;
                            vv = 0.5f * vv * (1.0f + erff(vv * 0.70710678118654752f));
                            Hb[(size_t)(rowbase + rl) * NDIM + col] = (short)f2bf(vv);
                        }
                    }
                }
            }
        } else {
            float* Op = (float*)outp;      // grouped-row order (coalesced tiles)
            #pragma unroll
            for (int n = 0; n < 4; ++n) {
                int col = colbase + wc + n * 16 + l15;
                float bv = bias[e * NDIM + col];
                #pragma unroll
                for (int m = 0; m < 4; ++m) {
                    int r0l = wr + m * 16 + l4 * 4;
                    #pragma unroll
                    for (int r = 0; r < 4; ++r) {
                        int rl = r0l + r;
                        if (rl < rmax)
                            Op[(size_t)(rowbase + rl) * NDIM + col] = acc[m][n][r] + bv;
                    }
                }
            }
        }
    }
}

// ---------------- residual + LN + weighted top-k combine (Op in grouped order)
__device__ inline float block_sum256(float v, volatile float* red, int tid)
{
    #pragma unroll
    for (int o = 32; o > 0; o >>= 1) v += __shfl_xor(v, o, 64);
    __syncthreads();
    if ((tid & 63) == 0) red[tid >> 6] = v;
    __syncthreads();
    return red[0] + red[1] + red[2] + red[3];
}

__global__ __launch_bounds__(256) void ln_combine_kernel(
    const float* __restrict__ Op, const float* __restrict__ x,
    const int* __restrict__ topk_i, const float* __restrict__ topk_w,
    const int* __restrict__ inv_row,
    const float* __restrict__ ln_g, const float* __restrict__ ln_b,
    float* __restrict__ y)
{
    __shared__ float red[4];
    const int t = blockIdx.x, tid = threadIdx.x;
    const float4 xr = *(const float4*)&x[(size_t)t * HD + tid * 4];
    float a0 = 0.f, a1 = 0.f, a2 = 0.f, a3 = 0.f;
    #pragma unroll
    for (int k = 0; k < TOPK; ++k) {
        int e = topk_i[t * 2 + k];
        float w = topk_w[t * 2 + k];
        int grow = inv_row[t * 2 + k];
        const float4 o = *(const float4*)&Op[(size_t)grow * HD + tid * 4];
        float v0 = o.x + xr.x, v1 = o.y + xr.y, v2 = o.z + xr.z, v3 = o.w + xr.w;
        float s = block_sum256(v0 + v1 + v2 + v3, red, tid);
        float m = s * (1.0f / HD);
        float d0 = v0 - m, d1 = v1 - m, d2 = v2 - m, d3 = v3 - m;
        float ssq = block_sum256(d0 * d0 + d1 * d1 + d2 * d2 + d3 * d3, red, tid);
        float inv = 1.0f / sqrtf(ssq * (1.0f / HD) + 1e-5f);
        int base = e * HD + tid * 4;
        const float4 g = *(const float4*)&ln_g[base];
        const float4 bb = *(const float4*)&ln_b[base];
        a0 += w * (d0 * inv * g.x + bb.x);
        a1 += w * (d1 * inv * g.y + bb.y);
        a2 += w * (d2 * inv * g.z + bb.z);
        a3 += w * (d3 * inv * g.w + bb.w);
    }
    *(float4*)&y[(size_t)t * HD + tid * 4] = make_float4(a0, a1, a2, a3);
}

__global__ void zero_out_kernel(float* __restrict__ y, int n)
{
    int i = blockIdx.x * 256 + threadIdx.x;
    if (i < n) y[i] = 0.f;
}

extern "C" void kernel_launch(void* const* d_in, const int* in_sizes, int n_in,
                              void* d_out, int out_size, void* d_ws, size_t ws_size,
                              hipStream_t stream)
{
    const float* x      = (const float*)d_in[0];
    const float* W1     = (const float*)d_in[1];
    const float* b1     = (const float*)d_in[2];
    const float* W2     = (const float*)d_in[3];
    const float* b2     = (const float*)d_in[4];
    const float* ln_g   = (const float*)d_in[5];
    const float* ln_b   = (const float*)d_in[6];
    const float* gn_g   = (const float*)d_in[7];
    const float* gn_b   = (const float*)d_in[8];
    const float* gate_w = (const float*)d_in[9];
    const float* gate_b = (const float*)d_in[10];
    float* y = (float*)d_out;

    char* ws = (char*)d_ws;
    size_t off = 0;
    auto take = [&](size_t b) -> char* {
        char* p = ws + off;
        off = (off + b + 255) & ~(size_t)255;
        return p;
    };
    short* W1T     = (short*)take((size_t)NE * FD * HD * 2);       // [E][F][H] bf16
    short* W2T     = (short*)take((size_t)NE * HD * FD * 2);       // [E][H][F] bf16
    short* Xg      = (short*)take((size_t)(NPAIR + PADR) * HD * 2);
    short* Hb      = (short*)take((size_t)(NPAIR + PADR) * FD * 2);
    float* Op      = (float*)take((size_t)NPAIR * HD * 4);         // grouped rows
    int*   topk_i  = (int*)take(NPAIR * 4);
    float* topk_w  = (float*)take(NPAIR * 4);
    int*   cnts    = (int*)take(64);            // 8 counts + 8 cursor
    int*   cursor  = cnts + 8;
    int*   offs    = (int*)take(64);
    int*   ts      = (int*)take(64);            // tile prefix (BM=128)
    int*   wctr    = (int*)take(64);            // 2 work counters
    int*   pair_tok= (int*)take((size_t)(NPAIR + PADR) * 4);
    int*   inv_row = (int*)take((size_t)NPAIR * 4);

    if (ws_size < off) {   // workspace too small: emit zeros so failure mode is diagnosable
        zero_out_kernel<<<(out_size + 255) / 256, 256, 0, stream>>>(y, out_size);
        return;
    }

    hipMemsetAsync(cnts, 0, 64, stream);
    hipMemsetAsync(wctr, 0, 64, stream);

    transpose_cvt_kernel<HD, FD><<<dim3(FD / 64, HD / 64, NE), 256, 0, stream>>>(W1, W1T);
    transpose_cvt_kernel<FD, HD><<<dim3(HD / 64, FD / 64, NE), 256, 0, stream>>>(W2, W2T);

    gating_kernel<<<TOK / 4, 256, 0, stream>>>(x, gn_g, gn_b, gate_w, gate_b, topk_i, topk_w, cnts);
    offsets_kernel<<<1, 64, 0, stream>>>(cnts, offs, ts);
    scatter_kernel<<<NPAIR / 256, 256, 0, stream>>>(topk_i, offs, cursor, pair_tok, inv_row);
    gather_kernel<<<NPAIR, 256, 0, stream>>>(x, pair_tok, Xg);

    // Persistent grouped GEMMs: grid = 256 (1 block/CU), atomic work list.
    // GEMM1: [pairs x HD] @ W1T -> gelu -> Hb   (items = tiles x 16 cols)
    gemm_kernel<HD, FD, 1, FD / BN><<<256, 512, 0, stream>>>(
        Xg, W1T, b1, (void*)Hb, cnts, offs, ts, wctr);
    // GEMM2: [pairs x FD] @ W2T -> +b2 -> Op   (items = tiles x 4 cols)
    gemm_kernel<FD, HD, 2, HD / BN><<<256, 512, 0, stream>>>(
        Hb, W2T, b2, (void*)Op, cnts, offs, ts, wctr + 1);

    ln_combine_kernel<<<TOK, 256, 0, stream>>>(Op, x, topk_i, topk_w, inv_row, ln_g, ln_b, y);
}

// Round 13
// 909.115 us; speedup vs baseline: 1.1797x; 1.1797x over previous
//
#include <hip/hip_runtime.h>
#include <hip/hip_bf16.h>

#define TOK   8192      // B*S
#define HD    1024      // H
#define FD    4096      // F
#define NE    8         // E
#define TOPK  2
#define NPAIR (TOK*TOPK)   // 16384, fixed
#define PADR  128          // row padding for tile overrun
#define BM    128
#define BN    256
#define BK    32
#define TMAX  (NPAIR/BM + NE)   // 136 grid rows; nwg stays %8==0

typedef short bf16x8 __attribute__((ext_vector_type(8)));
typedef float f32x4  __attribute__((ext_vector_type(4)));

__device__ inline unsigned short f2bf(float f) {
    unsigned u = __float_as_uint(f);
    unsigned r = (u + 0x7fffu + ((u >> 16) & 1u)) >> 16;
    return (unsigned short)r;
}

// ---------------- transpose + fp32->bf16 convert: in [E][R][C] -> out [E][C][R]
template<int R, int C>
__global__ __launch_bounds__(256) void transpose_cvt_kernel(
    const float* __restrict__ in, short* __restrict__ out)
{
    __shared__ float tile[64][65];
    const int tid = threadIdx.x;
    const int c0 = blockIdx.x * 64, r0 = blockIdx.y * 64, e = blockIdx.z;
    #pragma unroll
    for (int i = 0; i < 4; ++i) {
        int idx = i * 1024 + tid * 4;
        int rr = idx >> 6, cc = idx & 63;
        float4 v = *(const float4*)&in[((size_t)e * R + r0 + rr) * C + c0 + cc];
        tile[rr][cc] = v.x; tile[rr][cc + 1] = v.y;
        tile[rr][cc + 2] = v.z; tile[rr][cc + 3] = v.w;
    }
    __syncthreads();
    #pragma unroll
    for (int i = 0; i < 8; ++i) {
        int idx = i * 256 + tid;
        int cc = idx >> 5, rp = idx & 31;
        unsigned lo = f2bf(tile[rp * 2][cc]);
        unsigned hi = f2bf(tile[rp * 2 + 1][cc]);
        unsigned w = lo | (hi << 16);
        *(unsigned*)&out[((size_t)e * C + c0 + cc) * R + r0 + rp * 2] = w;
    }
}

// ---------------- gating: fp64 LN + logits + softmax + top-2 (one wave per token)
__global__ __launch_bounds__(256) void gating_kernel(
    const float* __restrict__ x, const float* __restrict__ gn_g, const float* __restrict__ gn_b,
    const float* __restrict__ gate_w, const float* __restrict__ gate_b,
    int* __restrict__ topk_i, float* __restrict__ topk_w, int* __restrict__ counts)
{
    const int wv = threadIdx.x >> 6, lane = threadIdx.x & 63;
    const int t = blockIdx.x * 4 + wv;
    const float* xr = x + (size_t)t * HD;

    double xs[16];
    #pragma unroll
    for (int i = 0; i < 16; ++i) xs[i] = (double)xr[i * 64 + lane];
    double s = 0.0;
    #pragma unroll
    for (int i = 0; i < 16; ++i) s += xs[i];
    #pragma unroll
    for (int o = 32; o > 0; o >>= 1) s += __shfl_xor(s, o, 64);
    double mean = s * (1.0 / HD);
    double ss = 0.0;
    #pragma unroll
    for (int i = 0; i < 16; ++i) { double d = xs[i] - mean; ss += d * d; }
    #pragma unroll
    for (int o = 32; o > 0; o >>= 1) ss += __shfl_xor(ss, o, 64);
    double inv = 1.0 / sqrt(ss * (1.0 / HD) + 1e-5);

    double ac[NE];
    #pragma unroll
    for (int e = 0; e < NE; ++e) ac[e] = 0.0;
    #pragma unroll
    for (int i = 0; i < 16; ++i) {
        int h = i * 64 + lane;
        double ln = (xs[i] - mean) * inv * (double)gn_g[h] + (double)gn_b[h];
        #pragma unroll
        for (int e = 0; e < NE; ++e) ac[e] += ln * (double)gate_w[h * NE + e];
    }
    #pragma unroll
    for (int e = 0; e < NE; ++e) {
        #pragma unroll
        for (int o = 32; o > 0; o >>= 1) ac[e] += __shfl_xor(ac[e], o, 64);
    }
    if (lane == 0) {
        double lg[NE], p[NE];
        double mx = -1e300;
        #pragma unroll
        for (int e = 0; e < NE; ++e) { lg[e] = ac[e] + (double)gate_b[e]; mx = lg[e] > mx ? lg[e] : mx; }
        double ps = 0.0;
        #pragma unroll
        for (int e = 0; e < NE; ++e) { p[e] = exp(lg[e] - mx); ps += p[e]; }
        #pragma unroll
        for (int e = 0; e < NE; ++e) p[e] /= ps;
        int i0 = 0;
        for (int e = 1; e < NE; ++e) if (p[e] > p[i0]) i0 = e;   // strict > keeps first (jax tie rule)
        int i1 = (i0 == 0) ? 1 : 0;
        for (int e = 0; e < NE; ++e) if (e != i0 && p[e] > p[i1]) i1 = e;
        double den = p[i0] + p[i1] + 1e-9;
        topk_i[t * 2] = i0; topk_i[t * 2 + 1] = i1;
        topk_w[t * 2] = (float)(p[i0] / den);
        topk_w[t * 2 + 1] = (float)(p[i1] / den);
        atomicAdd(&counts[i0], 1);
        atomicAdd(&counts[i1], 1);
    }
}

// ---------------- tiny prefix sums: row offsets + BM-row tile prefix
__global__ void offsets_kernel(const int* __restrict__ counts,
                               int* __restrict__ offs, int* __restrict__ ts)
{
    if (threadIdx.x == 0) {
        int s = 0, t = 0;
        for (int e = 0; e < NE; ++e) {
            offs[e] = s; ts[e] = t;
            s += counts[e];
            t += (counts[e] + BM - 1) / BM;
        }
        offs[NE] = s; ts[NE] = t;
    }
}

// ---------------- scatter pair ids into expert-grouped list (+ inverse map)
__global__ __launch_bounds__(256) void scatter_kernel(
    const int* __restrict__ topk_i, const int* __restrict__ offs,
    int* __restrict__ cursor, int* __restrict__ pair_tok, int* __restrict__ inv_row)
{
    int idx = blockIdx.x * 256 + threadIdx.x;   // pair id = t*2+k
    if (idx < NPAIR) {
        int e = topk_i[idx];
        int pos = atomicAdd(&cursor[e], 1);
        int dst = offs[e] + pos;
        pair_tok[dst] = idx;
        inv_row[idx] = dst;
    }
}

// ---------------- gather x rows (fp32) -> Xg (bf16, grouped order)
__global__ __launch_bounds__(256) void gather_kernel(
    const float* __restrict__ x, const int* __restrict__ pair_tok, short* __restrict__ Xg)
{
    const int r = blockIdx.x;
    const int t = pair_tok[r] >> 1;
    const int tid = threadIdx.x;
    float4 v = *(const float4*)&x[(size_t)t * HD + tid * 4];
    unsigned w0 = (unsigned)f2bf(v.x) | ((unsigned)f2bf(v.y) << 16);
    unsigned w1 = (unsigned)f2bf(v.z) | ((unsigned)f2bf(v.w) << 16);
    *(uint2*)&Xg[(size_t)r * HD + tid * 4] = make_uint2(w0, w1);
}

// counted-vmcnt boundary: allow N loads (per wave) to stay in flight, then barrier.
#define WAITB(n) do {                                                   \
    asm volatile("s_waitcnt vmcnt(" #n ")" ::: "memory");               \
    __builtin_amdgcn_s_barrier();                                       \
    __builtin_amdgcn_sched_barrier(0);                                  \
} while (0)

#define GLOAD(srcp, dstp) __builtin_amdgcn_global_load_lds(                         \
        (const __attribute__((address_space(1))) unsigned*)(srcp),                  \
        (__attribute__((address_space(3))) unsigned*)(dstp), 16, 0, 0)

// ---------------- grouped GEMM, flat-tile balanced grid: ONE 128x256 output tile
// per block (grid = NCOL x TMAX; block j=by via ts[] prefix -> (expert, row tile);
// j >= ts[NE] exits). Max skew = 1 tile -> no slot quantization (r5-r11) and no
// dynamic-scheduling locality loss (r12). K-loop = r7 verbatim (best measured):
// BK=32, 3-slot LDS ring (72 KB, 2 blk/CU), counted vmcnt(3) 2-K-tile prefetch,
// 8 waves (2M x 4N), wave tile 64x64, granule swizzle (conflicts=0, r6/r7):
// phys 16B-granule g of row r holds global granule g^((r>>1)&3), pre-swizzled
// global source + swizzled ds_read addr (rule #21).
// EPI==1: gelu -> bf16 Hbuf ; EPI==2: +bias -> fp32 Op (both grouped rows)
template<int KDIM, int NDIM, int EPI>
__global__ __launch_bounds__(512, 4) void gemm_kernel(
    const short* __restrict__ A, const short* __restrict__ BT,
    const float* __restrict__ bias, void* __restrict__ outp,
    const int* __restrict__ counts, const int* __restrict__ offs,
    const int* __restrict__ ts)
{
    // bijective XCD swizzle (nwg % 8 == 0: 16*136=2176, 4*136=544)
    const int nwg = gridDim.x * gridDim.y;
    const int orig = blockIdx.y * gridDim.x + blockIdx.x;
    const int v = (orig & 7) * (nwg >> 3) + (orig >> 3);
    const int bx = v % gridDim.x;             // col tile
    const int j = v / gridDim.x;              // global row tile

    if (j >= ts[NE]) return;                  // inactive tail block (block-uniform)

    int e = 0;
    #pragma unroll
    for (int k = 1; k < NE; ++k) if (j >= ts[k]) e = k;
    const int cnt = counts[e];
    const int rt = j - ts[e];
    const int rowbase = offs[e] + rt * BM;
    const int colbase = bx * BN;

    const int tid = threadIdx.x;

    // 3-slot ring: As 3 x [128][32], Bs 3 x [256][32] -> 72 KB total
    __shared__ __align__(16) short As[3 * BM * BK];
    __shared__ __align__(16) short Bs[3 * BN * BK];

    const int lane = tid & 63;
    const int wv = tid >> 6;                  // 8 waves: 2 M-groups x 4 N-groups
    const int wr = (wv >> 2) * 64, wc = (wv & 3) * 64;
    const int l15 = lane & 15, l4 = lane >> 4;

    // staging: A = 4096 shorts (1 granule/thread), B = 8192 shorts (2 granules/thread)
    const int se0 = tid * 8;                  // LDS short index, rows 0..127
    const int sr0 = se0 >> 5;                 // staging row
    const int sg0 = (se0 >> 3) & 3;           // physical 16B granule within row
    const int sr1 = sr0 + 128;                // B pass 1 rows 128..255
    // pre-swizzled global k-offset (shorts): phys granule g holds global granule g^((r>>1)&3)
    const int sk0 = ((sg0 ^ ((sr0 >> 1) & 3)) << 3);
    const int sk1 = ((sg0 ^ ((sr1 >> 1) & 3)) << 3);

    // ds_read offsets (shorts), hoisted: logical granule l4 of row r at phys g = l4^((r>>1)&3)
    int aoff[4], boff[4];
    #pragma unroll
    for (int m = 0; m < 4; ++m) {
        int r = wr + m * 16 + l15;
        aoff[m] = r * BK + ((l4 ^ ((r >> 1) & 3)) << 3);
    }
    #pragma unroll
    for (int n = 0; n < 4; ++n) {
        int r = wc + n * 16 + l15;
        boff[n] = r * BK + ((l4 ^ ((r >> 1) & 3)) << 3);
    }

    const size_t bbase = (size_t)e * NDIM + colbase;

#define STAGE(sl, k0) do {                                                                \
        short* asl = &As[(sl) * (BM * BK)];                                               \
        short* bsl = &Bs[(sl) * (BN * BK)];                                               \
        const short* a0s = A + (size_t)(rowbase + sr0) * KDIM + (k0) + sk0;               \
        GLOAD(a0s, &asl[se0]);                                                            \
        const short* b0s = BT + (bbase + sr0) * KDIM + (k0) + sk0;                        \
        GLOAD(b0s, &bsl[se0]);                                                            \
        const short* b1s = BT + (bbase + sr1) * KDIM + (k0) + sk1;                        \
        GLOAD(b1s, &bsl[se0 + 4096]);                                                     \
    } while (0)

    constexpr int NT = KDIM / BK;

    // prologue: stage tiles 0 and 1; wait tile 0 (allow tile 1's 3 loads in flight)
    STAGE(0, 0);
    STAGE(1, BK);
    WAITB(3);

    f32x4 acc[4][4];
    #pragma unroll
    for (int m = 0; m < 4; ++m)
        #pragma unroll
        for (int n = 0; n < 4; ++n)
            acc[m][n] = (f32x4){0.f, 0.f, 0.f, 0.f};

    for (int t = 0; t < NT; ++t) {
        if (t + 2 < NT) STAGE((t + 2) % 3, (t + 2) * BK);   // 2-K-tile prefetch

        const short* asl = &As[(t % 3) * (BM * BK)];
        const short* bsl = &Bs[(t % 3) * (BN * BK)];
        bf16x8 a[4], b[4];
        #pragma unroll
        for (int m = 0; m < 4; ++m)
            a[m] = *(const bf16x8*)&asl[aoff[m]];
        #pragma unroll
        for (int n = 0; n < 4; ++n)
            b[n] = *(const bf16x8*)&bsl[boff[n]];

        __builtin_amdgcn_s_setprio(1);
        #pragma unroll
        for (int m = 0; m < 4; ++m)
            #pragma unroll
            for (int n = 0; n < 4; ++n)
                acc[m][n] = __builtin_amdgcn_mfma_f32_16x16x32_bf16(a[m], b[n], acc[m][n], 0, 0, 0);
        __builtin_amdgcn_s_setprio(0);

        // boundary into tile t+1: counted wait (tile t+1 staged a full K-step ago;
        // only tile t+2's 3 loads may remain in flight). Last boundary drains.
        if (t < NT - 1) {
            if (t == NT - 2) WAITB(0); else WAITB(3);
        }
    }
#undef STAGE

    const int rmax = cnt - rt * BM;   // valid rows in this tile (tail tiles < BM)

    if (EPI == 1) {
        short* Hb = (short*)outp;
        #pragma unroll
        for (int n = 0; n < 4; ++n) {
            int col = colbase + wc + n * 16 + l15;
            float bv = bias[e * NDIM + col];
            #pragma unroll
            for (int m = 0; m < 4; ++m) {
                int r0l = wr + m * 16 + l4 * 4;
                #pragma unroll
                for (int r = 0; r < 4; ++r) {
                    int rl = r0l + r;
                    if (rl < rmax) {   // guard: do NOT clobber next expert's rows
                        float vv = acc[m][n][r] + bv;
                        vv = 0.5f * vv * (1.0f + erff(vv * 0.70710678118654752f));
                        Hb[(size_t)(rowbase + rl) * NDIM + col] = (short)f2bf(vv);
                    }
                }
            }
        }
    } else {
        float* Op = (float*)outp;      // grouped-row order (coalesced tiles)
        #pragma unroll
        for (int n = 0; n < 4; ++n) {
            int col = colbase + wc + n * 16 + l15;
            float bv = bias[e * NDIM + col];
            #pragma unroll
            for (int m = 0; m < 4; ++m) {
                int r0l = wr + m * 16 + l4 * 4;
                #pragma unroll
                for (int r = 0; r < 4; ++r) {
                    int rl = r0l + r;
                    if (rl < rmax)
                        Op[(size_t)(rowbase + rl) * NDIM + col] = acc[m][n][r] + bv;
                }
            }
        }
    }
}

// ---------------- residual + LN + weighted top-k combine (Op in grouped order)
__device__ inline float block_sum256(float v, volatile float* red, int tid)
{
    #pragma unroll
    for (int o = 32; o > 0; o >>= 1) v += __shfl_xor(v, o, 64);
    __syncthreads();
    if ((tid & 63) == 0) red[tid >> 6] = v;
    __syncthreads();
    return red[0] + red[1] + red[2] + red[3];
}

__global__ __launch_bounds__(256) void ln_combine_kernel(
    const float* __restrict__ Op, const float* __restrict__ x,
    const int* __restrict__ topk_i, const float* __restrict__ topk_w,
    const int* __restrict__ inv_row,
    const float* __restrict__ ln_g, const float* __restrict__ ln_b,
    float* __restrict__ y)
{
    __shared__ float red[4];
    const int t = blockIdx.x, tid = threadIdx.x;
    const float4 xr = *(const float4*)&x[(size_t)t * HD + tid * 4];
    float a0 = 0.f, a1 = 0.f, a2 = 0.f, a3 = 0.f;
    #pragma unroll
    for (int k = 0; k < TOPK; ++k) {
        int e = topk_i[t * 2 + k];
        float w = topk_w[t * 2 + k];
        int grow = inv_row[t * 2 + k];
        const float4 o = *(const float4*)&Op[(size_t)grow * HD + tid * 4];
        float v0 = o.x + xr.x, v1 = o.y + xr.y, v2 = o.z + xr.z, v3 = o.w + xr.w;
        float s = block_sum256(v0 + v1 + v2 + v3, red, tid);
        float m = s * (1.0f / HD);
        float d0 = v0 - m, d1 = v1 - m, d2 = v2 - m, d3 = v3 - m;
        float ssq = block_sum256(d0 * d0 + d1 * d1 + d2 * d2 + d3 * d3, red, tid);
        float inv = 1.0f / sqrtf(ssq * (1.0f / HD) + 1e-5f);
        int base = e * HD + tid * 4;
        const float4 g = *(const float4*)&ln_g[base];
        const float4 bb = *(const float4*)&ln_b[base];
        a0 += w * (d0 * inv * g.x + bb.x);
        a1 += w * (d1 * inv * g.y + bb.y);
        a2 += w * (d2 * inv * g.z + bb.z);
        a3 += w * (d3 * inv * g.w + bb.w);
    }
    *(float4*)&y[(size_t)t * HD + tid * 4] = make_float4(a0, a1, a2, a3);
}

__global__ void zero_out_kernel(float* __restrict__ y, int n)
{
    int i = blockIdx.x * 256 + threadIdx.x;
    if (i < n) y[i] = 0.f;
}

extern "C" void kernel_launch(void* const* d_in, const int* in_sizes, int n_in,
                              void* d_out, int out_size, void* d_ws, size_t ws_size,
                              hipStream_t stream)
{
    const float* x      = (const float*)d_in[0];
    const float* W1     = (const float*)d_in[1];
    const float* b1     = (const float*)d_in[2];
    const float* W2     = (const float*)d_in[3];
    const float* b2     = (const float*)d_in[4];
    const float* ln_g   = (const float*)d_in[5];
    const float* ln_b   = (const float*)d_in[6];
    const float* gn_g   = (const float*)d_in[7];
    const float* gn_b   = (const float*)d_in[8];
    const float* gate_w = (const float*)d_in[9];
    const float* gate_b = (const float*)d_in[10];
    float* y = (float*)d_out;

    char* ws = (char*)d_ws;
    size_t off = 0;
    auto take = [&](size_t b) -> char* {
        char* p = ws + off;
        off = (off + b + 255) & ~(size_t)255;
        return p;
    };
    short* W1T     = (short*)take((size_t)NE * FD * HD * 2);       // [E][F][H] bf16
    short* W2T     = (short*)take((size_t)NE * HD * FD * 2);       // [E][H][F] bf16
    short* Xg      = (short*)take((size_t)(NPAIR + PADR) * HD * 2);
    short* Hb      = (short*)take((size_t)(NPAIR + PADR) * FD * 2);
    float* Op      = (float*)take((size_t)NPAIR * HD * 4);         // grouped rows
    int*   topk_i  = (int*)take(NPAIR * 4);
    float* topk_w  = (float*)take(NPAIR * 4);
    int*   cnts    = (int*)take(64);            // 8 counts + 8 cursor
    int*   cursor  = cnts + 8;
    int*   offs    = (int*)take(64);
    int*   ts      = (int*)take(64);            // tile prefix (BM=128)
    int*   pair_tok= (int*)take((size_t)(NPAIR + PADR) * 4);
    int*   inv_row = (int*)take((size_t)NPAIR * 4);

    if (ws_size < off) {   // workspace too small: emit zeros so failure mode is diagnosable
        zero_out_kernel<<<(out_size + 255) / 256, 256, 0, stream>>>(y, out_size);
        return;
    }

    hipMemsetAsync(cnts, 0, 64, stream);

    transpose_cvt_kernel<HD, FD><<<dim3(FD / 64, HD / 64, NE), 256, 0, stream>>>(W1, W1T);
    transpose_cvt_kernel<FD, HD><<<dim3(HD / 64, FD / 64, NE), 256, 0, stream>>>(W2, W2T);

    gating_kernel<<<TOK / 4, 256, 0, stream>>>(x, gn_g, gn_b, gate_w, gate_b, topk_i, topk_w, cnts);
    offsets_kernel<<<1, 64, 0, stream>>>(cnts, offs, ts);
    scatter_kernel<<<NPAIR / 256, 256, 0, stream>>>(topk_i, offs, cursor, pair_tok, inv_row);
    gather_kernel<<<NPAIR, 256, 0, stream>>>(x, pair_tok, Xg);

    // Flat-tile balanced grouped GEMMs: grid = (cols, TMAX) with per-block ts[] lookup.
    // GEMM1: [pairs x HD] @ W1T -> gelu -> Hb   (16 x 136 = 2176 blocks)
    gemm_kernel<HD, FD, 1><<<dim3(FD / BN, TMAX), 512, 0, stream>>>(
        Xg, W1T, b1, (void*)Hb, cnts, offs, ts);
    // GEMM2: [pairs x FD] @ W2T -> +b2 -> Op   (4 x 136 = 544 blocks)
    gemm_kernel<FD, HD, 2><<<dim3(HD / BN, TMAX), 512, 0, stream>>>(
        Hb, W2T, b2, (void*)Op, cnts, offs, ts);

    ln_combine_kernel<<<TOK, 256, 0, stream>>>(Op, x, topk_i, topk_w, inv_row, ln_g, ln_b, y);
}